// Round 4
// baseline (560.553 us; speedup 1.0000x reference)
//
#include <hip/hip_runtime.h>

#define NROWS   13107200u        // 32*640*640
#define HW      409600u          // 640*640
#define N4      (NROWS/4u)       // 3,276,800 float4-groups
#define TPB     256
#define BLOCKS  2560             // N4/THREADS = 5 groups/thread exactly
#define THREADS (BLOCKS*TPB)     // 655,360

// OHEM tail histogram: only negatives with se >= 5.0 can matter.
// cutoff quantile k/negC ~= 15.8%; P(se>=5 | neg) ~= 28.7% -> 1.81x margin.
#define BIN0    2068u            // __float_as_uint(5.0f)>>19
#define NBINS   512              // bins [5.0, 2^34); top bin = clamp/overflow detector
#define NCOPY   4                // replicated LDS histograms
#define CSTRIDE 513              // +1 skew across copies

// fallback (full-range, old scheme) -- runs only if finish sets ctl->flag
#define FCBINS   4096
#define FNCOPY   4
#define FCSTRIDE 4097
#define FBLOCKS  512
#define FTHREADS (FBLOCKS*TPB)   // 131,072
#define FITERS   25              // N4 / FTHREADS exactly

struct Ctl {
  double posLoss;     // sum of se*w over all elements (negs contribute 0)
  double sumW;        // sum of w
  unsigned posCnt;    // exact count of w>0 elements
  unsigned flag;      // 1 -> fallback path must produce the answer
};

__device__ inline float wredf(float v) {
  #pragma unroll
  for (int o = 32; o > 0; o >>= 1) v += __shfl_down(v, o, 64);
  return v;
}
__device__ inline unsigned wredu(unsigned v) {
  #pragma unroll
  for (int o = 32; o > 0; o >>= 1) v += __shfl_down(v, o, 64);
  return v;
}

__device__ inline void procGroup(const float4& w4, const float4& p0, const float4& p1,
                                 const float4& t0, const float4& t1,
                                 float& posLoss, float& sumW, unsigned& posCnt,
                                 unsigned* lh, unsigned copyOff)
{
  float se[4], wv[4];
  {
    float a, c;
    a = p0.x - t0.x; c = p1.x - t1.x; se[0] = a*a + c*c;
    a = p0.y - t0.y; c = p1.y - t1.y; se[1] = a*a + c*c;
    a = p0.z - t0.z; c = p1.z - t1.z; se[2] = a*a + c*c;
    a = p0.w - t0.w; c = p1.w - t1.w; se[3] = a*a + c*c;
  }
  wv[0] = w4.x; wv[1] = w4.y; wv[2] = w4.z; wv[3] = w4.w;
  #pragma unroll
  for (int c = 0; c < 4; ++c) {
    const float w = wv[c];
    const float s = se[c];
    posLoss = fmaf(s, w, posLoss);
    sumW += w;
    posCnt += (w > 0.f) ? 1u : 0u;
    int idx = (int)(__float_as_uint(s) >> 19) - (int)BIN0;  // >=0 iff se>=5.0
    if (w == 0.f && idx >= 0) {
      idx = idx < (int)(NBINS - 1) ? idx : (int)(NBINS - 1); // clamp -> fallback flag
      atomicAdd(&lh[copyOff + (unsigned)idx], 1u);
    }
  }
}

// Fully-unrolled 2-stage software pipeline: at every sched_barrier there are
// 10 float4 loads in flight (two groups). sched_barrier(0) prevents the
// scheduler from sinking the load batch to its uses (the v1/v3 failure mode:
// VGPR squeezed to 20-28, loads serialized, eff. BW dropped 2.0->1.1 TB/s).
#define LOADG(W,P0,P1,T0,T1,MM) do {                                          \
    const unsigned g_ = tid + (unsigned)(MM) * THREADS;                       \
    const unsigned i_ = g_ << 2;                                              \
    const unsigned b_ = i_ / HW;          /* 4-group never crosses batch */   \
    const size_t base_ = (size_t)b_ * (size_t)(2u * HW) + (size_t)(i_ - b_ * HW); \
    W  = *(const float4*)(wgt + i_);                                          \
    P0 = *(const float4*)(pred + base_);                                      \
    P1 = *(const float4*)(pred + base_ + HW);                                 \
    T0 = *(const float4*)(vmk + base_);                                       \
    T1 = *(const float4*)(vmk + base_ + HW);                                  \
  } while (0)

#define CONS(W,P0,P1,T0,T1) \
  procGroup(W, P0, P1, T0, T1, posLoss, sumW, posCnt, lh, copyOff)

__global__ __launch_bounds__(TPB, 4)   // 128-VGPR budget, 4 blocks/CU resident
void mainpass(const float* __restrict__ pred, const float* __restrict__ vmk,
              const float* __restrict__ wgt, Ctl* __restrict__ ctl,
              unsigned* __restrict__ ghist)
{
  __shared__ unsigned lh[NCOPY * CSTRIDE];   // 8,208 B
  for (int j = threadIdx.x; j < NCOPY * CSTRIDE; j += TPB) lh[j] = 0;
  __syncthreads();

  float posLoss = 0.f, sumW = 0.f;
  unsigned posCnt = 0;
  const unsigned tid = blockIdx.x * TPB + threadIdx.x;
  const unsigned copyOff = (threadIdx.x & (NCOPY - 1)) * CSTRIDE;

  float4 wA, p0A, p1A, t0A, t1A;
  float4 wB, p0B, p1B, t0B, t1B;

  LOADG(wA, p0A, p1A, t0A, t1A, 0);
  LOADG(wB, p0B, p1B, t0B, t1B, 1);
  __builtin_amdgcn_sched_barrier(0);
  CONS(wA, p0A, p1A, t0A, t1A);            // group 0
  LOADG(wA, p0A, p1A, t0A, t1A, 2);
  __builtin_amdgcn_sched_barrier(0);
  CONS(wB, p0B, p1B, t0B, t1B);            // group 1
  LOADG(wB, p0B, p1B, t0B, t1B, 3);
  __builtin_amdgcn_sched_barrier(0);
  CONS(wA, p0A, p1A, t0A, t1A);            // group 2
  LOADG(wA, p0A, p1A, t0A, t1A, 4);
  __builtin_amdgcn_sched_barrier(0);
  CONS(wB, p0B, p1B, t0B, t1B);            // group 3
  CONS(wA, p0A, p1A, t0A, t1A);            // group 4

  posLoss = wredf(posLoss); sumW = wredf(sumW); posCnt = wredu(posCnt);
  if ((threadIdx.x & 63) == 0) {
    atomicAdd(&ctl->posLoss, (double)posLoss);
    atomicAdd(&ctl->sumW, (double)sumW);
    atomicAdd(&ctl->posCnt, posCnt);
  }
  __syncthreads();
  for (int bn = threadIdx.x; bn < NBINS; bn += TPB) {
    unsigned c = 0;
    #pragma unroll
    for (int r = 0; r < NCOPY; ++r) c += lh[r * CSTRIDE + bn];
    if (c) atomicAdd(&ghist[bn], c);     // zero-skip: few hundred populated bins
  }
}

// One block. Parallel suffix scan over 256 chunks (2 bins each), then the
// unique crossing thread finishes. Sets ctl->flag if the tail histogram
// cannot cover rank k (cutoff below se=5.0 or overflow clamp occurred).
__global__ __launch_bounds__(256)
void finish(Ctl* __restrict__ ctl, const unsigned* __restrict__ ghist,
            float* __restrict__ out)
{
  __shared__ unsigned sC[256];
  __shared__ double   sS[256];
  __shared__ unsigned s_flag, s_k;
  const int t = threadIdx.x;

  const unsigned b0 = 2u * (unsigned)t, b1 = b0 + 1u;
  const unsigned c0 = ghist[b0], c1 = ghist[b1];
  double s0 = 0.0, s1 = 0.0;
  if (c0) {
    const double lo = (double)__uint_as_float((b0 + BIN0) << 19);
    const double hi = (double)__uint_as_float((b0 + BIN0 + 1u) << 19);
    s0 = (double)c0 * 0.5 * (lo + hi);
  }
  if (c1) {
    const double lo = (double)__uint_as_float((b1 + BIN0) << 19);
    const double hi = (double)__uint_as_float((b1 + BIN0 + 1u) << 19);
    s1 = (double)c1 * 0.5 * (lo + hi);
  }
  sC[t] = c0 + c1; sS[t] = s0 + s1;
  __syncthreads();

  // suffix-inclusive Hillis-Steele: sC[t] = sum_{j>=t} chunkC[j]
  for (int off = 1; off < 256; off <<= 1) {
    unsigned c = sC[t]; double s = sS[t];
    if (t + off < 256) { c += sC[t + off]; s += sS[t + off]; }
    __syncthreads();
    sC[t] = c; sS[t] = s;
    __syncthreads();
  }

  if (t == 0) {
    const unsigned posC = ctl->posCnt;
    const unsigned negC = NROWS - posC;          // data has no w<0 / NaN weights
    const unsigned long long k3 = 3ull * (unsigned long long)posC;
    const unsigned k = (k3 < (unsigned long long)negC) ? (unsigned)k3 : negC;
    s_k = k;
    s_flag = (k > 0 && (sC[0] < k || ghist[NBINS - 1] != 0u)) ? 1u : 0u;
    if (s_flag) ctl->flag = 1u;
  }
  __syncthreads();
  if (s_flag) return;                            // fallback kernels will answer
  const unsigned k = s_k;

  if (k == 0) {
    if (t == 0) {
      const double num = ctl->posLoss;
      double den = 2.0 * ctl->sumW;
      if (den == 0.0) den = 1.0;
      out[0] = (float)(num / den / 32.0);
    }
    return;
  }

  const unsigned above = (t < 255) ? sC[t + 1] : 0u;
  if (sC[t] >= k && above < k) {                 // exactly one thread
    unsigned A = above;
    double S = (t < 255) ? sS[t + 1] : 0.0;
    unsigned bi, cnt;
    if (A + c1 >= k) { bi = b1; cnt = c1; }
    else             { A += c1; S += s1; bi = b0; cnt = c0; }
    const unsigned need = k - A;                 // 1 <= need <= cnt
    const double lo = (double)__uint_as_float((bi + BIN0) << 19);
    const double hi = (double)__uint_as_float((bi + BIN0 + 1u) << 19);
    const double q = (double)need / (double)cnt;
    const double sel = S + (double)need * (hi - 0.5 * q * (hi - lo));
    const double num = ctl->posLoss + sel;
    double den = 2.0 * ctl->sumW + 2.0 * (double)k;
    if (den == 0.0) den = 1.0;
    out[0] = (float)(num / den / 32.0);
  }
}

// ---- fallback path (normally early-exits; correctness net for any data) ----

__global__ __launch_bounds__(TPB)
void fb_main(const float* __restrict__ pred, const float* __restrict__ vmk,
             const float* __restrict__ wgt, const Ctl* __restrict__ ctl,
             unsigned* __restrict__ ghist2)
{
  __shared__ unsigned go;
  if (threadIdx.x == 0) go = ctl->flag;
  __syncthreads();
  if (!go) return;

  __shared__ unsigned lh[FNCOPY * FCSTRIDE];     // 65,552 B (rare path)
  for (int j = threadIdx.x; j < FNCOPY * FCSTRIDE; j += TPB) lh[j] = 0;
  __syncthreads();

  const unsigned tid = blockIdx.x * TPB + threadIdx.x;
  const unsigned copyOff = (threadIdx.x & (FNCOPY - 1)) * FCSTRIDE;

  #pragma unroll 1
  for (int m = 0; m < FITERS; ++m) {
    const unsigned g = tid + (unsigned)m * FTHREADS;
    const unsigned i = g << 2;
    const unsigned b = i / HW;
    const unsigned hw = i - b * HW;
    const size_t base = (size_t)b * (size_t)(2u * HW) + (size_t)hw;
    const float4 w4 = *(const float4*)(wgt + i);
    const float4 p0 = *(const float4*)(pred + base);
    const float4 p1 = *(const float4*)(pred + base + HW);
    const float4 t0 = *(const float4*)(vmk + base);
    const float4 t1 = *(const float4*)(vmk + base + HW);
    float se[4], wv[4];
    {
      float a, c;
      a = p0.x - t0.x; c = p1.x - t1.x; se[0] = a*a + c*c;
      a = p0.y - t0.y; c = p1.y - t1.y; se[1] = a*a + c*c;
      a = p0.z - t0.z; c = p1.z - t1.z; se[2] = a*a + c*c;
      a = p0.w - t0.w; c = p1.w - t1.w; se[3] = a*a + c*c;
    }
    wv[0] = w4.x; wv[1] = w4.y; wv[2] = w4.z; wv[3] = w4.w;
    #pragma unroll
    for (int c = 0; c < 4; ++c) {
      if (wv[c] == 0.f) {
        const unsigned bin = __float_as_uint(se[c]) >> 19;
        atomicAdd(&lh[copyOff + bin], 1u);
      }
    }
  }
  __syncthreads();
  for (int bn = threadIdx.x; bn < FCBINS; bn += TPB) {
    unsigned c = 0;
    #pragma unroll
    for (int r = 0; r < FNCOPY; ++r) c += lh[r * FCSTRIDE + bn];
    if (c) atomicAdd(&ghist2[bn], c);
  }
}

__global__ __launch_bounds__(256)
void fb_finish(const Ctl* __restrict__ ctl, const unsigned* __restrict__ ghist2,
               float* __restrict__ out)
{
  if (ctl->flag == 0u) return;   // uniform across the block

  __shared__ unsigned chunkC[256];
  __shared__ double   chunkS[256];
  __shared__ unsigned binC[16];
  __shared__ double   binS[16];
  __shared__ int s_cc;
  __shared__ unsigned s_A, s_k;
  __shared__ double s_S;
  const int t = threadIdx.x;
  const unsigned posC = ctl->posCnt;

  {
    unsigned c = 0; double s = 0.0;
    #pragma unroll
    for (int j = 0; j < FCBINS / 256; ++j) {
      const unsigned bi = (unsigned)(t * (FCBINS / 256) + j);
      const unsigned cnt = ghist2[bi];
      if (cnt) {
        const double lo = (double)__uint_as_float(bi << 19);
        const double hi = (double)__uint_as_float((bi + 1u) << 19);
        c += cnt;
        s += (double)cnt * 0.5 * (lo + hi);
      }
    }
    chunkC[t] = c; chunkS[t] = s;
  }
  __syncthreads();
  if (t == 0) {
    const unsigned negC = NROWS - posC;
    const unsigned long long k3 = 3ull * (unsigned long long)posC;
    const unsigned k = (k3 < (unsigned long long)negC) ? (unsigned)k3 : negC;
    s_k = k;
    if (k == 0) { s_cc = -1; s_A = 0; s_S = 0.0; }
    else {
      unsigned A = 0; double S = 0.0;
      int cc = 255;
      for (; cc >= 0; --cc) {
        if (A + chunkC[cc] >= k) break;
        A += chunkC[cc]; S += chunkS[cc];
      }
      s_cc = cc; s_A = A; s_S = S;
    }
  }
  __syncthreads();
  const int cc = s_cc;
  if (cc >= 0 && t < 16) {
    const unsigned bi = (unsigned)(cc * 16 + t);
    const unsigned cnt = ghist2[bi];
    binC[t] = cnt;
    if (cnt) {
      const double lo = (double)__uint_as_float(bi << 19);
      const double hi = (double)__uint_as_float((bi + 1u) << 19);
      binS[t] = (double)cnt * 0.5 * (lo + hi);
    } else binS[t] = 0.0;
  }
  __syncthreads();
  if (t == 0) {
    const unsigned k = s_k;
    double sel = 0.0;
    if (k > 0) {
      unsigned A = s_A; double S = s_S;
      int j = 15;
      for (;; --j) {
        const unsigned c = binC[j];
        if (A + c >= k) {
          const unsigned need = k - A;
          const unsigned bi = (unsigned)(cc * 16 + j);
          const double lo = (double)__uint_as_float(bi << 19);
          const double hi = (double)__uint_as_float((bi + 1u) << 19);
          const double q = (double)need / (double)c;
          sel = S + (double)need * (hi - 0.5 * q * (hi - lo));
          break;
        }
        A += c; S += binS[j];
      }
    }
    const double num = ctl->posLoss + sel;
    double den = 2.0 * ctl->sumW + 2.0 * (double)s_k;
    if (den == 0.0) den = 1.0;
    out[0] = (float)(num / den / 32.0);
  }
}

extern "C" void kernel_launch(void* const* d_in, const int* in_sizes, int n_in,
                              void* d_out, int out_size, void* d_ws, size_t ws_size,
                              hipStream_t stream)
{
  const float* pred = (const float*)d_in[0];
  const float* vmk  = (const float*)d_in[1];
  const float* wgt  = (const float*)d_in[2];
  char* ws = (char*)d_ws;
  Ctl* ctl         = (Ctl*)ws;
  unsigned* ghist  = (unsigned*)(ws + 64);
  unsigned* ghist2 = (unsigned*)(ws + 64 + NBINS * 4);
  const size_t head = 64 + NBINS * 4 + FCBINS * 4;   // 18,496 B

  hipMemsetAsync(d_ws, 0, head, stream);  // ws re-poisoned 0xAA before every call
  mainpass<<<BLOCKS, TPB, 0, stream>>>(pred, vmk, wgt, ctl, ghist);
  finish<<<1, 256, 0, stream>>>(ctl, ghist, (float*)d_out);
  fb_main<<<FBLOCKS, TPB, 0, stream>>>(pred, vmk, wgt, ctl, ghist2);
  fb_finish<<<1, 256, 0, stream>>>(ctl, ghist2, (float*)d_out);
}

// Round 5
// 321.906 us; speedup vs baseline: 1.7414x; 1.7414x over previous
//
#include <hip/hip_runtime.h>

#define NROWS   13107200u        // 32*640*640
#define HW      409600u          // 640*640
#define N4      (NROWS/4u)       // 3,276,800 float4-groups
#define TPB     256
#define BLOCKS  512              // 2 blocks/CU resident (LDS-capped) -- v0 config
#define THREADS (BLOCKS*TPB)     // 131,072 -> exactly 25 groups/thread
#define ITERS   25

// OHEM tail histogram: only negatives with se >= 5.0 can matter.
// cutoff quantile k/negC ~= 15.8%; P(se>=5 | neg) ~= 28.7% -> 1.81x margin.
#define BIN0    2068u            // __float_as_uint(5.0f)>>19
#define NBINS   512              // bins [5.0, 2^34); top bin = clamp/overflow detector
#define NCOPY   32               // 32 replicas: lane&31 -> copy; 65.7 KB keeps the
#define CSTRIDE 513              // compiler in v0's register-rich, 2-blk/CU regime

// fallback (full-range histogram) -- runs only if finish sets ctl->flag
#define FCBINS   4096
#define FNCOPY   4
#define FCSTRIDE 4097
#define FBLOCKS  512
#define FTHREADS (FBLOCKS*TPB)   // 131,072
#define FITERS   25              // N4 / FTHREADS exactly

struct Ctl {
  double posLoss;     // sum of se*w over all elements (negs contribute 0)
  double sumW;        // sum of w
  unsigned posCnt;    // exact count of w>0 elements
  unsigned flag;      // 1 -> fallback path must produce the answer
};

__device__ inline float wredf(float v) {
  #pragma unroll
  for (int o = 32; o > 0; o >>= 1) v += __shfl_down(v, o, 64);
  return v;
}
__device__ inline unsigned wredu(unsigned v) {
  #pragma unroll
  for (int o = 32; o > 0; o >>= 1) v += __shfl_down(v, o, 64);
  return v;
}

// v0's exact loop structure (512 blocks x 25 iters, 66-KB-class LDS ->
// compiler allocates ~88 VGPR and keeps 5 float4 loads in flight; measured
// 2.0 TB/s delivered). Only change vs v0: histogram is the 512-bin se>=5.0
// negative tail (27% of lanes) instead of an unconditional per-lane atomic,
// and 32 replicas instead of 4.
__global__ __launch_bounds__(TPB)
void mainpass(const float* __restrict__ pred, const float* __restrict__ vmk,
              const float* __restrict__ wgt, Ctl* __restrict__ ctl,
              unsigned* __restrict__ ghist)
{
  __shared__ unsigned lh[NCOPY * CSTRIDE];   // 65,664 B
  for (int j = threadIdx.x; j < NCOPY * CSTRIDE; j += TPB) lh[j] = 0;
  __syncthreads();

  float posLoss = 0.f, sumW = 0.f;
  unsigned posCnt = 0;
  const unsigned tid = blockIdx.x * TPB + threadIdx.x;
  const unsigned copyOff = (threadIdx.x & (NCOPY - 1)) * CSTRIDE;

  #pragma unroll 1
  for (int m = 0; m < ITERS; ++m) {
    const unsigned g = tid + (unsigned)m * THREADS;
    const unsigned i = g << 2;
    const unsigned b = i / HW;            // 4-group never crosses batch (HW%4==0)
    const unsigned hw = i - b * HW;
    const size_t base = (size_t)b * (size_t)(2u * HW) + (size_t)hw;
    const float4 w4 = *(const float4*)(wgt + i);
    const float4 p0 = *(const float4*)(pred + base);
    const float4 p1 = *(const float4*)(pred + base + HW);
    const float4 t0 = *(const float4*)(vmk + base);
    const float4 t1 = *(const float4*)(vmk + base + HW);
    float se[4], wv[4];
    {
      float a, c;
      a = p0.x - t0.x; c = p1.x - t1.x; se[0] = a*a + c*c;
      a = p0.y - t0.y; c = p1.y - t1.y; se[1] = a*a + c*c;
      a = p0.z - t0.z; c = p1.z - t1.z; se[2] = a*a + c*c;
      a = p0.w - t0.w; c = p1.w - t1.w; se[3] = a*a + c*c;
    }
    wv[0] = w4.x; wv[1] = w4.y; wv[2] = w4.z; wv[3] = w4.w;
    #pragma unroll
    for (int c = 0; c < 4; ++c) {
      const float w = wv[c];
      const float s = se[c];
      posLoss = fmaf(s, w, posLoss);     // v_fmac
      sumW += w;                         // v_add
      posCnt += (w > 0.f) ? 1u : 0u;
      int idx = (int)(__float_as_uint(s) >> 19) - (int)BIN0;  // >=0 iff se>=5.0
      if (w == 0.f && idx >= 0) {        // ~27% of lanes active
        idx = idx < (int)(NBINS - 1) ? idx : (int)(NBINS - 1); // clamp -> fallback
        atomicAdd(&lh[copyOff + (unsigned)idx], 1u);
      }
    }
  }

  posLoss = wredf(posLoss); sumW = wredf(sumW); posCnt = wredu(posCnt);
  if ((threadIdx.x & 63) == 0) {
    atomicAdd(&ctl->posLoss, (double)posLoss);
    atomicAdd(&ctl->sumW, (double)sumW);
    atomicAdd(&ctl->posCnt, posCnt);
  }
  __syncthreads();
  for (int bn = threadIdx.x; bn < NBINS; bn += TPB) {
    unsigned c = 0;
    #pragma unroll
    for (int r = 0; r < NCOPY; ++r) c += lh[r * CSTRIDE + bn];
    if (c) atomicAdd(&ghist[bn], c);     // zero-skip: few hundred populated bins
  }
}

// One block. Parallel suffix scan over 256 chunks (2 bins each), then the
// unique crossing thread finishes. Sets ctl->flag if the tail histogram
// cannot cover rank k (cutoff below se=5.0 or overflow clamp occurred).
__global__ __launch_bounds__(256)
void finish(Ctl* __restrict__ ctl, const unsigned* __restrict__ ghist,
            float* __restrict__ out)
{
  __shared__ unsigned sC[256];
  __shared__ double   sS[256];
  __shared__ unsigned s_flag, s_k;
  const int t = threadIdx.x;

  const unsigned b0 = 2u * (unsigned)t, b1 = b0 + 1u;
  const unsigned c0 = ghist[b0], c1 = ghist[b1];
  double s0 = 0.0, s1 = 0.0;
  if (c0) {
    const double lo = (double)__uint_as_float((b0 + BIN0) << 19);
    const double hi = (double)__uint_as_float((b0 + BIN0 + 1u) << 19);
    s0 = (double)c0 * 0.5 * (lo + hi);
  }
  if (c1) {
    const double lo = (double)__uint_as_float((b1 + BIN0) << 19);
    const double hi = (double)__uint_as_float((b1 + BIN0 + 1u) << 19);
    s1 = (double)c1 * 0.5 * (lo + hi);
  }
  sC[t] = c0 + c1; sS[t] = s0 + s1;
  __syncthreads();

  // suffix-inclusive Hillis-Steele: sC[t] = sum_{j>=t} chunkC[j]
  for (int off = 1; off < 256; off <<= 1) {
    unsigned c = sC[t]; double s = sS[t];
    if (t + off < 256) { c += sC[t + off]; s += sS[t + off]; }
    __syncthreads();
    sC[t] = c; sS[t] = s;
    __syncthreads();
  }

  if (t == 0) {
    const unsigned posC = ctl->posCnt;
    const unsigned negC = NROWS - posC;          // data has no w<0 / NaN weights
    const unsigned long long k3 = 3ull * (unsigned long long)posC;
    const unsigned k = (k3 < (unsigned long long)negC) ? (unsigned)k3 : negC;
    s_k = k;
    s_flag = (k > 0 && (sC[0] < k || ghist[NBINS - 1] != 0u)) ? 1u : 0u;
    if (s_flag) ctl->flag = 1u;
  }
  __syncthreads();
  if (s_flag) return;                            // fallback kernels will answer
  const unsigned k = s_k;

  if (k == 0) {
    if (t == 0) {
      const double num = ctl->posLoss;
      double den = 2.0 * ctl->sumW;
      if (den == 0.0) den = 1.0;
      out[0] = (float)(num / den / 32.0);
    }
    return;
  }

  const unsigned above = (t < 255) ? sC[t + 1] : 0u;
  if (sC[t] >= k && above < k) {                 // exactly one thread
    unsigned A = above;
    double S = (t < 255) ? sS[t + 1] : 0.0;
    unsigned bi, cnt;
    if (A + c1 >= k) { bi = b1; cnt = c1; }
    else             { A += c1; S += s1; bi = b0; cnt = c0; }
    const unsigned need = k - A;                 // 1 <= need <= cnt
    const double lo = (double)__uint_as_float((bi + BIN0) << 19);
    const double hi = (double)__uint_as_float((bi + BIN0 + 1u) << 19);
    const double q = (double)need / (double)cnt;
    const double sel = S + (double)need * (hi - 0.5 * q * (hi - lo));
    const double num = ctl->posLoss + sel;
    double den = 2.0 * ctl->sumW + 2.0 * (double)k;
    if (den == 0.0) den = 1.0;
    out[0] = (float)(num / den / 32.0);
  }
}

// ---- fallback path (normally early-exits; correctness net for any data) ----

__global__ __launch_bounds__(TPB)
void fb_main(const float* __restrict__ pred, const float* __restrict__ vmk,
             const float* __restrict__ wgt, const Ctl* __restrict__ ctl,
             unsigned* __restrict__ ghist2)
{
  __shared__ unsigned go;
  if (threadIdx.x == 0) go = ctl->flag;
  __syncthreads();
  if (!go) return;

  __shared__ unsigned lh[FNCOPY * FCSTRIDE];     // 65,552 B (rare path)
  for (int j = threadIdx.x; j < FNCOPY * FCSTRIDE; j += TPB) lh[j] = 0;
  __syncthreads();

  const unsigned tid = blockIdx.x * TPB + threadIdx.x;
  const unsigned copyOff = (threadIdx.x & (FNCOPY - 1)) * FCSTRIDE;

  #pragma unroll 1
  for (int m = 0; m < FITERS; ++m) {
    const unsigned g = tid + (unsigned)m * FTHREADS;
    const unsigned i = g << 2;
    const unsigned b = i / HW;
    const unsigned hw = i - b * HW;
    const size_t base = (size_t)b * (size_t)(2u * HW) + (size_t)hw;
    const float4 w4 = *(const float4*)(wgt + i);
    const float4 p0 = *(const float4*)(pred + base);
    const float4 p1 = *(const float4*)(pred + base + HW);
    const float4 t0 = *(const float4*)(vmk + base);
    const float4 t1 = *(const float4*)(vmk + base + HW);
    float se[4], wv[4];
    {
      float a, c;
      a = p0.x - t0.x; c = p1.x - t1.x; se[0] = a*a + c*c;
      a = p0.y - t0.y; c = p1.y - t1.y; se[1] = a*a + c*c;
      a = p0.z - t0.z; c = p1.z - t1.z; se[2] = a*a + c*c;
      a = p0.w - t0.w; c = p1.w - t1.w; se[3] = a*a + c*c;
    }
    wv[0] = w4.x; wv[1] = w4.y; wv[2] = w4.z; wv[3] = w4.w;
    #pragma unroll
    for (int c = 0; c < 4; ++c) {
      if (wv[c] == 0.f) {
        const unsigned bin = __float_as_uint(se[c]) >> 19;
        atomicAdd(&lh[copyOff + bin], 1u);
      }
    }
  }
  __syncthreads();
  for (int bn = threadIdx.x; bn < FCBINS; bn += TPB) {
    unsigned c = 0;
    #pragma unroll
    for (int r = 0; r < FNCOPY; ++r) c += lh[r * FCSTRIDE + bn];
    if (c) atomicAdd(&ghist2[bn], c);
  }
}

__global__ __launch_bounds__(256)
void fb_finish(const Ctl* __restrict__ ctl, const unsigned* __restrict__ ghist2,
               float* __restrict__ out)
{
  if (ctl->flag == 0u) return;   // uniform across the block

  __shared__ unsigned chunkC[256];
  __shared__ double   chunkS[256];
  __shared__ unsigned binC[16];
  __shared__ double   binS[16];
  __shared__ int s_cc;
  __shared__ unsigned s_A, s_k;
  __shared__ double s_S;
  const int t = threadIdx.x;
  const unsigned posC = ctl->posCnt;

  {
    unsigned c = 0; double s = 0.0;
    #pragma unroll
    for (int j = 0; j < FCBINS / 256; ++j) {
      const unsigned bi = (unsigned)(t * (FCBINS / 256) + j);
      const unsigned cnt = ghist2[bi];
      if (cnt) {
        const double lo = (double)__uint_as_float(bi << 19);
        const double hi = (double)__uint_as_float((bi + 1u) << 19);
        c += cnt;
        s += (double)cnt * 0.5 * (lo + hi);
      }
    }
    chunkC[t] = c; chunkS[t] = s;
  }
  __syncthreads();
  if (t == 0) {
    const unsigned negC = NROWS - posC;
    const unsigned long long k3 = 3ull * (unsigned long long)posC;
    const unsigned k = (k3 < (unsigned long long)negC) ? (unsigned)k3 : negC;
    s_k = k;
    if (k == 0) { s_cc = -1; s_A = 0; s_S = 0.0; }
    else {
      unsigned A = 0; double S = 0.0;
      int cc = 255;
      for (; cc >= 0; --cc) {
        if (A + chunkC[cc] >= k) break;
        A += chunkC[cc]; S += chunkS[cc];
      }
      s_cc = cc; s_A = A; s_S = S;
    }
  }
  __syncthreads();
  const int cc = s_cc;
  if (cc >= 0 && t < 16) {
    const unsigned bi = (unsigned)(cc * 16 + t);
    const unsigned cnt = ghist2[bi];
    binC[t] = cnt;
    if (cnt) {
      const double lo = (double)__uint_as_float(bi << 19);
      const double hi = (double)__uint_as_float((bi + 1u) << 19);
      binS[t] = (double)cnt * 0.5 * (lo + hi);
    } else binS[t] = 0.0;
  }
  __syncthreads();
  if (t == 0) {
    const unsigned k = s_k;
    double sel = 0.0;
    if (k > 0) {
      unsigned A = s_A; double S = s_S;
      int j = 15;
      for (;; --j) {
        const unsigned c = binC[j];
        if (A + c >= k) {
          const unsigned need = k - A;
          const unsigned bi = (unsigned)(cc * 16 + j);
          const double lo = (double)__uint_as_float(bi << 19);
          const double hi = (double)__uint_as_float((bi + 1u) << 19);
          const double q = (double)need / (double)c;
          sel = S + (double)need * (hi - 0.5 * q * (hi - lo));
          break;
        }
        A += c; S += binS[j];
      }
    }
    const double num = ctl->posLoss + sel;
    double den = 2.0 * ctl->sumW + 2.0 * (double)s_k;
    if (den == 0.0) den = 1.0;
    out[0] = (float)(num / den / 32.0);
  }
}

extern "C" void kernel_launch(void* const* d_in, const int* in_sizes, int n_in,
                              void* d_out, int out_size, void* d_ws, size_t ws_size,
                              hipStream_t stream)
{
  const float* pred = (const float*)d_in[0];
  const float* vmk  = (const float*)d_in[1];
  const float* wgt  = (const float*)d_in[2];
  char* ws = (char*)d_ws;
  Ctl* ctl         = (Ctl*)ws;
  unsigned* ghist  = (unsigned*)(ws + 64);
  unsigned* ghist2 = (unsigned*)(ws + 64 + NBINS * 4);
  const size_t head = 64 + NBINS * 4 + FCBINS * 4;   // 18,496 B

  hipMemsetAsync(d_ws, 0, head, stream);  // ws re-poisoned 0xAA before every call
  mainpass<<<BLOCKS, TPB, 0, stream>>>(pred, vmk, wgt, ctl, ghist);
  finish<<<1, 256, 0, stream>>>(ctl, ghist, (float*)d_out);
  fb_main<<<FBLOCKS, TPB, 0, stream>>>(pred, vmk, wgt, ctl, ghist2);
  fb_finish<<<1, 256, 0, stream>>>(ctl, ghist2, (float*)d_out);
}